// Round 1
// baseline (125.651 us; speedup 1.0000x reference)
//
#include <hip/hip_runtime.h>
#include <math.h>

#define N 1024
#define D 512
#define NC 16

static constexpr float THRESH    = 0.5f;
static constexpr float MARGIN    = 0.1f;
static constexpr float SCALE_POS = 0.05f;
static constexpr float SCALE_NEG = 0.002f;
static constexpr float EPS_      = 1e-5f;

// ---------------------------------------------------------------------------
// Kernel 1: sim = F * F^T  (fp32 vector GEMM, 64x64 tiles, BK=16, 4x4/thread)
// ---------------------------------------------------------------------------
__global__ __launch_bounds__(256) void gemm_ffT(const float* __restrict__ F,
                                                float* __restrict__ S) {
    __shared__ float As[64][17];   // +1 pad breaks pow2 strides
    __shared__ float Bs[64][17];
    const int tid = threadIdx.x;
    const int tc  = tid & 15;      // 0..15 col group
    const int tr  = tid >> 4;      // 0..15 row group
    const int row0 = blockIdx.y * 64;
    const int col0 = blockIdx.x * 64;

    float acc[4][4] = {};

    for (int k0 = 0; k0 < D; k0 += 16) {
        // load 64x16 A-tile and B-tile, 4 elems/thread each
        #pragma unroll
        for (int l = 0; l < 4; ++l) {
            const int r = (tid >> 4) + l * 16;   // 0..63
            const int k = tid & 15;
            As[r][k] = F[(row0 + r) * D + k0 + k];
            Bs[r][k] = F[(col0 + r) * D + k0 + k];
        }
        __syncthreads();
        #pragma unroll
        for (int kk = 0; kk < 16; ++kk) {
            float a[4], b[4];
            #pragma unroll
            for (int m = 0; m < 4; ++m) a[m] = As[tr * 4 + m][kk];
            #pragma unroll
            for (int n = 0; n < 4; ++n) b[n] = Bs[tc * 4 + n][kk];
            #pragma unroll
            for (int m = 0; m < 4; ++m)
                #pragma unroll
                for (int n = 0; n < 4; ++n)
                    acc[m][n] += a[m] * b[n];
        }
        __syncthreads();
    }
    #pragma unroll
    for (int m = 0; m < 4; ++m)
        #pragma unroll
        for (int n = 0; n < 4; ++n)
            S[(row0 + tr * 4 + m) * N + col0 + tc * 4 + n] = acc[m][n];
}

// ---------------------------------------------------------------------------
// Kernel 2: pack label bits per sample (bit c = labels[j][c]==1), count anchors
// ---------------------------------------------------------------------------
__global__ void pack_labels(const int* __restrict__ labels,
                            unsigned* __restrict__ mask,
                            int* __restrict__ total) {
    const int j = blockIdx.x * blockDim.x + threadIdx.x;   // 0..1023
    unsigned m = 0;
    int cnt = 0;
    #pragma unroll
    for (int c = 0; c < NC; ++c) {
        if (labels[j * NC + c] == 1) { m |= (1u << c); ++cnt; }
    }
    mask[j] = m;
    #pragma unroll
    for (int off = 32; off; off >>= 1) cnt += __shfl_down(cnt, off, 64);
    if ((threadIdx.x & 63) == 0) atomicAdd(total, cnt);
}

// ---------------------------------------------------------------------------
// Kernel 3: per-row multi-similarity reduction. One block per anchor row i.
// ---------------------------------------------------------------------------
__global__ __launch_bounds__(256) void ms_reduce(const float* __restrict__ S,
                                                 const unsigned* __restrict__ mask,
                                                 const int* __restrict__ labels,
                                                 double* __restrict__ loss_acc) {
    const int i    = blockIdx.x;
    const int tid  = threadIdx.x;
    const int lane = tid & 63;
    const int wave = tid >> 6;

    __shared__ float red_min[NC][4];
    __shared__ float red_max[NC][4];
    __shared__ float s_mpe[NC];    // min_pos_eff per class
    __shared__ float s_mxn[NC];    // max_neg per class
    __shared__ float red_ps[NC][4];
    __shared__ float red_ns[NC][4];

    // each thread owns j = tid + 256*l, l = 0..3
    float    s[4];
    unsigned mk[4];
    #pragma unroll
    for (int l = 0; l < 4; ++l) {
        const int j = tid + 256 * l;
        s[l]  = S[i * N + j];
        mk[l] = mask[j];
    }

    // ---- pass 1: min_pos (over lab_pos & sim<1-eps) and max_neg (over lab_neg)
    for (int c = 0; c < NC; ++c) {
        float mn = INFINITY, mx = -INFINITY;
        #pragma unroll
        for (int l = 0; l < 4; ++l) {
            const bool pos  = (mk[l] >> c) & 1u;
            const bool posm = pos && (s[l] < 1.0f - EPS_);
            mn = fminf(mn, posm ? s[l] : INFINITY);
            mx = fmaxf(mx, pos ? -INFINITY : s[l]);
        }
        #pragma unroll
        for (int off = 32; off; off >>= 1) {
            mn = fminf(mn, __shfl_down(mn, off, 64));
            mx = fmaxf(mx, __shfl_down(mx, off, 64));
        }
        if (lane == 0) { red_min[c][wave] = mn; red_max[c][wave] = mx; }
    }
    __syncthreads();
    if (tid < NC) {
        const int c = tid;
        const float mn = fminf(fminf(red_min[c][0], red_min[c][1]),
                               fminf(red_min[c][2], red_min[c][3]));
        const float mx = fmaxf(fmaxf(red_max[c][0], red_max[c][1]),
                               fmaxf(red_max[c][2], red_max[c][3]));
        s_mpe[c] = (mn < INFINITY) ? mn : -INFINITY;   // pos_cnt>0 ? min_pos : -inf
        s_mxn[c] = mx;
    }
    __syncthreads();

    // ---- pass 2: selected exp sums
    float epos[4], eneg[4];
    #pragma unroll
    for (int l = 0; l < 4; ++l) {
        epos[l] = expf(-SCALE_POS * (s[l] - THRESH));
        eneg[l] = expf( SCALE_NEG * (s[l] - THRESH));
    }
    for (int c = 0; c < NC; ++c) {
        const float mpe = s_mpe[c];
        const float mxn = s_mxn[c];
        float ps = 0.0f, ns = 0.0f;
        #pragma unroll
        for (int l = 0; l < 4; ++l) {
            const bool pos  = (mk[l] >> c) & 1u;
            const bool posm = pos && (s[l] < 1.0f - EPS_);
            const bool psel = posm && (s[l] - MARGIN < mxn);
            const bool nsel = (!pos) && (s[l] + MARGIN > mpe);
            ps += psel ? epos[l] : 0.0f;
            ns += nsel ? eneg[l] : 0.0f;
        }
        #pragma unroll
        for (int off = 32; off; off >>= 1) {
            ps += __shfl_down(ps, off, 64);
            ns += __shfl_down(ns, off, 64);
        }
        if (lane == 0) { red_ps[c][wave] = ps; red_ns[c][wave] = ns; }
    }
    __syncthreads();

    // ---- per-class loss, block sum, one double atomic per block
    double lc = 0.0;
    if (tid < NC) {
        const int c = tid;
        const float ps = red_ps[c][0] + red_ps[c][1] + red_ps[c][2] + red_ps[c][3];
        const float ns = red_ns[c][0] + red_ns[c][1] + red_ns[c][2] + red_ns[c][3];
        const bool anchor = labels[i * NC + c] == 1;
        // ps>0 <=> count(pos_sel)>0 (every term >= e^-0.075); same for ns
        if (anchor && ps > 0.0f && ns > 0.0f) {
            lc = (double)(log1pf(ps) / SCALE_POS) + (double)(log1pf(ns) / SCALE_NEG);
        }
    }
    if (wave == 0) {
        #pragma unroll
        for (int off = 8; off; off >>= 1) lc += __shfl_down(lc, off, 64);
        if (lane == 0) atomicAdd(loss_acc, lc);
    }
}

// ---------------------------------------------------------------------------
// Kernel 4: finalize scalar
// ---------------------------------------------------------------------------
__global__ void finalize(const double* __restrict__ loss_acc,
                         const int* __restrict__ total,
                         float* __restrict__ out) {
    const double t = (double)(*total);
    out[0] = (t > 0.0) ? (float)(*loss_acc / t) : 0.0f;
}

// ---------------------------------------------------------------------------
extern "C" void kernel_launch(void* const* d_in, const int* in_sizes, int n_in,
                              void* d_out, int out_size, void* d_ws, size_t ws_size,
                              hipStream_t stream) {
    (void)in_sizes; (void)n_in; (void)out_size; (void)ws_size;
    const float* feats  = (const float*)d_in[0];
    const int*   labels = (const int*)d_in[1];
    float*       out    = (float*)d_out;

    // workspace layout: [0,4MB) sim | 4MB mask(4KB) | 4MB+4KB: double loss, int total
    char* ws = (char*)d_ws;
    float*    sim      = (float*)ws;
    unsigned* mask     = (unsigned*)(ws + (size_t)N * N * sizeof(float));
    double*   loss_acc = (double*)(ws + (size_t)N * N * sizeof(float) + 4096);
    int*      total    = (int*)(ws + (size_t)N * N * sizeof(float) + 4096 + 8);

    hipMemsetAsync(ws + (size_t)N * N * sizeof(float) + 4096, 0, 16, stream);

    dim3 gg(N / 64, N / 64);
    gemm_ffT<<<gg, 256, 0, stream>>>(feats, sim);
    pack_labels<<<N / 256, 256, 0, stream>>>(labels, mask, total);
    ms_reduce<<<N, 256, 0, stream>>>(sim, mask, labels, loss_acc);
    finalize<<<1, 1, 0, stream>>>(loss_acc, total, out);
}

// Round 2
// 92.961 us; speedup vs baseline: 1.3517x; 1.3517x over previous
//
#include <hip/hip_runtime.h>
#include <math.h>

#define N 1024
#define D 512
#define NC 16

static constexpr float THRESH    = 0.5f;
static constexpr float MARGIN    = 0.1f;
static constexpr float SCALE_POS = 0.05f;
static constexpr float SCALE_NEG = 0.002f;
static constexpr float EPS_      = 1e-5f;

typedef __bf16 bf16x8 __attribute__((ext_vector_type(8)));
typedef float  f32x4  __attribute__((ext_vector_type(4)));
typedef unsigned short ushort8v __attribute__((ext_vector_type(8)));

__device__ __forceinline__ unsigned short f2bf_rne(float x) {
    unsigned u = __builtin_bit_cast(unsigned, x);
    return (unsigned short)((u + 0x7FFFu + ((u >> 16) & 1u)) >> 16);
}

// ---------------------------------------------------------------------------
// Kernel 0: fp32 -> bf16 convert (8 elems/thread) + label bit-pack + anchor cnt
// ---------------------------------------------------------------------------
__global__ __launch_bounds__(256) void prep(const float* __restrict__ F,
                                            const int* __restrict__ labels,
                                            unsigned short* __restrict__ Fb,
                                            unsigned* __restrict__ mask,
                                            int* __restrict__ total) {
    const int idx = blockIdx.x * 256 + threadIdx.x;   // 65536 threads
    // --- convert 8 floats ---
    const float4* src = (const float4*)F;
    float4 v0 = src[idx * 2];
    float4 v1 = src[idx * 2 + 1];
    ushort8v o;
    o[0] = f2bf_rne(v0.x); o[1] = f2bf_rne(v0.y);
    o[2] = f2bf_rne(v0.z); o[3] = f2bf_rne(v0.w);
    o[4] = f2bf_rne(v1.x); o[5] = f2bf_rne(v1.y);
    o[6] = f2bf_rne(v1.z); o[7] = f2bf_rne(v1.w);
    *(ushort8v*)(Fb + idx * 8) = o;

    // --- pack labels (first 1024 threads, i.e. blocks 0..3) ---
    if (idx < N) {
        const int4* lp = (const int4*)(labels + idx * NC);
        unsigned m = 0;
        int cnt = 0;
        #pragma unroll
        for (int q = 0; q < 4; ++q) {
            int4 l4 = lp[q];
            if (l4.x == 1) { m |= 1u << (q * 4 + 0); ++cnt; }
            if (l4.y == 1) { m |= 1u << (q * 4 + 1); ++cnt; }
            if (l4.z == 1) { m |= 1u << (q * 4 + 2); ++cnt; }
            if (l4.w == 1) { m |= 1u << (q * 4 + 3); ++cnt; }
        }
        mask[idx] = m;
        #pragma unroll
        for (int off = 32; off; off >>= 1) cnt += __shfl_down(cnt, off, 64);
        if ((threadIdx.x & 63) == 0) atomicAdd(total, cnt);
    }
}

// ---------------------------------------------------------------------------
// Kernel 1: sim = Fb * Fb^T via MFMA bf16, no LDS (both frags load contiguous)
// block: 256 thr = 4 waves; tile 64x64; wave w -> m-strip [16w,16w+16) x 64 n
// ---------------------------------------------------------------------------
__global__ __launch_bounds__(256) void gemm_mfma(const unsigned short* __restrict__ Fbu,
                                                 float* __restrict__ S) {
    const __bf16* Fb = (const __bf16*)Fbu;
    const int tid  = threadIdx.x;
    const int wave = tid >> 6;
    const int lane = tid & 63;
    const int row0 = blockIdx.y * 64 + wave * 16;
    const int col0 = blockIdx.x * 64;
    const int lr = lane & 15;         // m (for A) / n (for B) within 16
    const int lk = (lane >> 4) * 8;   // k sub-offset

    const __bf16* pa = Fb + (size_t)(row0 + lr) * D + lk;
    const __bf16* pb0 = Fb + (size_t)(col0 + lr) * D + lk;
    const __bf16* pb1 = pb0 + 16 * D;
    const __bf16* pb2 = pb0 + 32 * D;
    const __bf16* pb3 = pb0 + 48 * D;

    f32x4 acc0 = {}, acc1 = {}, acc2 = {}, acc3 = {};

    #pragma unroll 4
    for (int k0 = 0; k0 < D; k0 += 32) {
        bf16x8 a  = *(const bf16x8*)(pa  + k0);
        bf16x8 b0 = *(const bf16x8*)(pb0 + k0);
        bf16x8 b1 = *(const bf16x8*)(pb1 + k0);
        bf16x8 b2 = *(const bf16x8*)(pb2 + k0);
        bf16x8 b3 = *(const bf16x8*)(pb3 + k0);
        acc0 = __builtin_amdgcn_mfma_f32_16x16x32_bf16(a, b0, acc0, 0, 0, 0);
        acc1 = __builtin_amdgcn_mfma_f32_16x16x32_bf16(a, b1, acc1, 0, 0, 0);
        acc2 = __builtin_amdgcn_mfma_f32_16x16x32_bf16(a, b2, acc2, 0, 0, 0);
        acc3 = __builtin_amdgcn_mfma_f32_16x16x32_bf16(a, b3, acc3, 0, 0, 0);
    }

    // C/D layout: col = lane&15, row = (lane>>4)*4 + reg
    const int r0 = row0 + (lane >> 4) * 4;
    const int c0 = col0 + lr;
    #pragma unroll
    for (int r = 0; r < 4; ++r) {
        float* Sr = S + (size_t)(r0 + r) * N + c0;
        Sr[0]  = acc0[r];
        Sr[16] = acc1[r];
        Sr[32] = acc2[r];
        Sr[48] = acc3[r];
    }
}

// ---------------------------------------------------------------------------
// Kernel 2: per-row MS reduction. Block = row i, wave w owns classes 4w..4w+3
// over all 1024 j (16 consecutive j per lane). shfl_xor butterflies; no
// sync between passes (each wave consumes only its own min/max).
// ---------------------------------------------------------------------------
__global__ __launch_bounds__(256) void ms_reduce(const float* __restrict__ S,
                                                 const unsigned* __restrict__ mask,
                                                 double* __restrict__ loss_acc) {
    const int i    = blockIdx.x;
    const int tid  = threadIdx.x;
    const int lane = tid & 63;
    const int wave = tid >> 6;
    const int cbase = wave * 4;

    float    s[16];
    unsigned mk[16];
    {
        const float4* Srow = (const float4*)(S + (size_t)i * N);
        const uint4*  Mrow = (const uint4*)mask;
        #pragma unroll
        for (int q = 0; q < 4; ++q) {
            float4 v = Srow[lane * 4 + q];
            uint4  m = Mrow[lane * 4 + q];
            s[q * 4 + 0] = v.x; s[q * 4 + 1] = v.y;
            s[q * 4 + 2] = v.z; s[q * 4 + 3] = v.w;
            mk[q * 4 + 0] = m.x; mk[q * 4 + 1] = m.y;
            mk[q * 4 + 2] = m.z; mk[q * 4 + 3] = m.w;
        }
    }

    // ---- pass 1: per-class min_pos / max_neg over this lane's 16 j ----
    float mn[4] = {INFINITY, INFINITY, INFINITY, INFINITY};
    float mx[4] = {-INFINITY, -INFINITY, -INFINITY, -INFINITY};
    #pragma unroll
    for (int u = 0; u < 16; ++u) {
        const float sv = s[u];
        const bool ok1 = sv < 1.0f - EPS_;
        #pragma unroll
        for (int cl = 0; cl < 4; ++cl) {
            const bool pos = (mk[u] >> (cbase + cl)) & 1u;
            mn[cl] = fminf(mn[cl], (pos && ok1) ? sv : INFINITY);
            mx[cl] = fmaxf(mx[cl], pos ? -INFINITY : sv);
        }
    }
    #pragma unroll
    for (int off = 32; off; off >>= 1) {
        #pragma unroll
        for (int cl = 0; cl < 4; ++cl) {
            mn[cl] = fminf(mn[cl], __shfl_xor(mn[cl], off, 64));
            mx[cl] = fmaxf(mx[cl], __shfl_xor(mx[cl], off, 64));
        }
    }
    float mpe[4], mxn[4];
    #pragma unroll
    for (int cl = 0; cl < 4; ++cl) {
        mpe[cl] = (mn[cl] < INFINITY) ? mn[cl] : -INFINITY;
        mxn[cl] = mx[cl];
    }

    // ---- pass 2: selected exp sums ----
    float ps[4] = {}, ns[4] = {};
    #pragma unroll
    for (int u = 0; u < 16; ++u) {
        const float sv = s[u];
        const float ep = expf(-SCALE_POS * (sv - THRESH));
        const float en = expf( SCALE_NEG * (sv - THRESH));
        const bool ok1 = sv < 1.0f - EPS_;
        const float sm = sv - MARGIN;
        const float sp = sv + MARGIN;
        #pragma unroll
        for (int cl = 0; cl < 4; ++cl) {
            const bool pos  = (mk[u] >> (cbase + cl)) & 1u;
            const bool psel = pos && ok1 && (sm < mxn[cl]);
            const bool nsel = (!pos) && (sp > mpe[cl]);
            ps[cl] += psel ? ep : 0.0f;
            ns[cl] += nsel ? en : 0.0f;
        }
    }
    #pragma unroll
    for (int off = 32; off; off >>= 1) {
        #pragma unroll
        for (int cl = 0; cl < 4; ++cl) {
            ps[cl] += __shfl_xor(ps[cl], off, 64);
            ns[cl] += __shfl_xor(ns[cl], off, 64);
        }
    }

    // ---- per-wave loss contribution, block-combine in LDS, 1 atomic ----
    __shared__ double part[4];
    if (lane == 0) {
        const unsigned am = mask[i];
        double lc = 0.0;
        #pragma unroll
        for (int cl = 0; cl < 4; ++cl) {
            const bool anchor = (am >> (cbase + cl)) & 1u;
            if (anchor && ps[cl] > 0.0f && ns[cl] > 0.0f) {
                lc += (double)(log1pf(ps[cl]) * (1.0f / SCALE_POS))
                    + (double)(log1pf(ns[cl]) * (1.0f / SCALE_NEG));
            }
        }
        part[wave] = lc;
    }
    __syncthreads();
    if (tid == 0) {
        atomicAdd(loss_acc, part[0] + part[1] + part[2] + part[3]);
    }
}

// ---------------------------------------------------------------------------
// Kernel 3: finalize scalar
// ---------------------------------------------------------------------------
__global__ void finalize(const double* __restrict__ loss_acc,
                         const int* __restrict__ total,
                         float* __restrict__ out) {
    const double t = (double)(*total);
    out[0] = (t > 0.0) ? (float)(*loss_acc / t) : 0.0f;
}

// ---------------------------------------------------------------------------
extern "C" void kernel_launch(void* const* d_in, const int* in_sizes, int n_in,
                              void* d_out, int out_size, void* d_ws, size_t ws_size,
                              hipStream_t stream) {
    (void)in_sizes; (void)n_in; (void)out_size; (void)ws_size;
    const float* feats  = (const float*)d_in[0];
    const int*   labels = (const int*)d_in[1];
    float*       out    = (float*)d_out;

    // ws layout: [0,4MB) sim | [4MB,5MB) bf16 feats | +4KB mask | accum
    char* ws = (char*)d_ws;
    float*          sim   = (float*)ws;
    unsigned short* Fb    = (unsigned short*)(ws + (size_t)N * N * 4);
    unsigned*       mask  = (unsigned*)(ws + (size_t)N * N * 4 + (size_t)N * D * 2);
    double* loss_acc = (double*)(ws + (size_t)N * N * 4 + (size_t)N * D * 2 + 4096);
    int*    total    = (int*)((char*)loss_acc + 8);

    hipMemsetAsync(loss_acc, 0, 16, stream);

    prep<<<(N * D / 8) / 256, 256, 0, stream>>>(feats, labels, Fb, mask, total);
    dim3 gg(N / 64, N / 64);
    gemm_mfma<<<gg, 256, 0, stream>>>(Fb, sim);
    ms_reduce<<<N, 256, 0, stream>>>(sim, mask, loss_acc);
    finalize<<<1, 1, 0, stream>>>(loss_acc, total, out);
}